// Round 1
// baseline (113.462 us; speedup 1.0000x reference)
//
#include <hip/hip_runtime.h>
#include <math.h>

#define N_TOT 8400
#define MASK_WORDS 132   // ceil(8400/64)
#define CAP 32           // max (word,bits) entries per row
#define RT 33            // rank tiles: ceil(8400/256)

typedef unsigned long long u64;

// monotone-increasing float->u32 mapping
__device__ __forceinline__ unsigned mono_u32(float f) {
    unsigned u = __float_as_uint(f);
    return (u & 0x80000000u) ? ~u : (u | 0x80000000u);
}

// ---------------- K1: decode all 3 scales + build sort keys + zero-init state ----------------
__global__ void decode_kernel(const float* __restrict__ score0, const float* __restrict__ bbox0, const float* __restrict__ kps0,
                              const float* __restrict__ score1, const float* __restrict__ bbox1, const float* __restrict__ kps1,
                              const float* __restrict__ score2, const float* __restrict__ bbox2, const float* __restrict__ kps2,
                              float* __restrict__ logit, float* __restrict__ sig,
                              float* __restrict__ box, float* __restrict__ kps,
                              u64* __restrict__ key, int* __restrict__ rank,
                              unsigned int* __restrict__ cnt,
                              u64* __restrict__ validw, u64* __restrict__ rowflag) {
    int i = blockIdx.x * blockDim.x + threadIdx.x;
    if (i >= N_TOT) return;
    if (i < MASK_WORDS) { validw[i] = 0ull; rowflag[i] = 0ull; }
    rank[i] = 0;
    cnt[i] = 0u;
    const float *sc, *bb, *kp;
    int m, F; float s;
    if (i < 6400)      { sc = score0; bb = bbox0; kp = kps0; m = i;        F = 80; s = 8.f;  }
    else if (i < 8000) { sc = score1; bb = bbox1; kp = kps1; m = i - 6400; F = 40; s = 16.f; }
    else               { sc = score2; bb = bbox2; kp = kps2; m = i - 8000; F = 20; s = 32.f; }
    float px = (float)(m % F) * s;
    float py = (float)(m / F) * s;
    float lg = sc[m];
    logit[i] = lg;
    sig[i] = 1.0f / (1.0f + expf(-lg));
    // descending-logit order with ascending-index tie-break, as one u64 key (ascending)
    key[i] = ((u64)(~mono_u32(lg)) << 14) | (u64)i;
    float d0 = bb[m*4+0]*s, d1 = bb[m*4+1]*s, d2 = bb[m*4+2]*s, d3 = bb[m*4+3]*s;
    box[i*4+0] = px - d0;
    box[i*4+1] = py - d1;
    box[i*4+2] = px + d2;
    box[i*4+3] = py + d3;
    #pragma unroll
    for (int c = 0; c < 5; ++c) {
        kps[i*10 + 2*c]   = px + kp[m*10 + 2*c]   * s;
        kps[i*10 + 2*c+1] = py + kp[m*10 + 2*c+1] * s;
    }
}

// ---------------- K2: tiled rank = #{j : key[j] < key[i]} ----------------
__global__ __launch_bounds__(256) void rank_kernel(const u64* __restrict__ key, int* __restrict__ rank) {
    __shared__ u64 tile[256];
    int i = blockIdx.x * 256 + threadIdx.x;
    int t0 = blockIdx.y * 256;
    u64 ki = (i < N_TOT) ? key[i] : 0ull;
    int j = t0 + threadIdx.x;
    tile[threadIdx.x] = (j < N_TOT) ? key[j] : ~0ull;   // OOB sorts last (never < ki)
    __syncthreads();
    if (i >= N_TOT) return;
    int rk = 0;
    #pragma unroll 8
    for (int k = 0; k < 256; ++k) {
        rk += (tile[k] < ki) ? 1 : 0;
    }
    if (rk) atomicAdd(&rank[i], rk);
}

// ---------------- K3: scatter into sorted order + set valid bits ----------------
__global__ void scatter_kernel(const int* __restrict__ rank,
                               const float* __restrict__ logit, const float* __restrict__ sig,
                               const float* __restrict__ box, const float* __restrict__ kps,
                               float* __restrict__ s_logit, float* __restrict__ s_sig,
                               float* __restrict__ s_box, float* __restrict__ s_kps,
                               u64* __restrict__ validw) {
    int i = blockIdx.x * blockDim.x + threadIdx.x;
    if (i >= N_TOT) return;
    int r = rank[i];
    float lg = logit[i];
    s_logit[r] = lg;
    s_sig[r] = sig[i];
    #pragma unroll
    for (int c = 0; c < 4; ++c)  s_box[r*4+c] = box[i*4+c];
    #pragma unroll
    for (int c = 0; c < 10; ++c) s_kps[r*10+c] = kps[i*10+c];
    if (lg > 0.f) atomicOr(&validw[r >> 6], 1ull << (r & 63));
}

// ---------------- K4: sparse successor-overlap pairs (branch-free inner loop) ----------------
// Triangular launch: grid (132, 67); wrap-map covers exactly {(rb,cw): 0<=rb<=cw<132}.
__global__ __launch_bounds__(64) void pairs_kernel(const float* __restrict__ s_logit,
                                                   const float* __restrict__ s_box,
                                                   unsigned int* __restrict__ cnt,
                                                   ulonglong2* __restrict__ ent,
                                                   u64* __restrict__ rowflag) {
    int x = blockIdx.x;   // 0..131
    int y = blockIdx.y;   // 0..66
    int rb, cw;
    if (x + y < MASK_WORDS) { rb = x; cw = x + y; }
    else {
        if (y == MASK_WORDS / 2) return;    // wrapped y=66 duplicates direct y=66
        rb = x + y - MASK_WORDS; cw = x;
    }
    int tid = threadIdx.x;

    __shared__ float4 cbox[64];
    __shared__ float  carea[64];
    int j0 = cw * 64;
    int j = j0 + tid;
    float4 cb = make_float4(0.f, 0.f, 0.f, 0.f);
    float lgj = -1.f;
    if (j < N_TOT) {
        cb = ((const float4*)s_box)[j];
        lgj = s_logit[j];
    }
    cbox[tid] = cb;
    carea[tid] = (cb.z - cb.x) * (cb.w - cb.y);
    u64 cvalid = __ballot(j < N_TOT && lgj > 0.f);
    __syncthreads();
    if (cvalid == 0ull) return;     // no valid columns (sorted => ranks >= V)

    int r = rb * 64 + tid;
    float lgr = (r < N_TOT) ? s_logit[r] : -1.f;
    if (__ballot(lgr > 0.f) == 0ull) return;   // whole wave of invalid rows

    u64 bits = 0ull;
    if (lgr > 0.f) {
        float4 rb4 = ((const float4*)s_box)[r];
        float rarea = (rb4.z - rb4.x) * (rb4.w - rb4.y);
        #pragma unroll 4
        for (int k = 0; k < 64; ++k) {
            float4 c4 = cbox[k];
            float ltx = fmaxf(rb4.x, c4.x);
            float lty = fmaxf(rb4.y, c4.y);
            float rbx = fminf(rb4.z, c4.z);
            float rby = fminf(rb4.w, c4.w);
            float w = fmaxf(rbx - ltx, 0.f);
            float h = fmaxf(rby - lty, 0.f);
            float inter = w * h;
            float iou = inter / (rarea + carea[k] - inter + 1e-9f);
            bits |= (iou > 0.4f) ? (1ull << k) : 0ull;
        }
        u64 m = cvalid;                                  // only valid columns
        if (cw == rb) m &= (tid == 63) ? 0ull : (~0ull << (tid + 1));  // only strict successors
        bits &= m;
    }
    if (bits) {
        unsigned idx = atomicAdd(&cnt[r], 1u);
        if (idx < CAP) {
            ulonglong2 e; e.x = bits; e.y = (u64)cw;
            ent[(size_t)r * CAP + idx] = e;
        }
        atomicOr(&rowflag[r >> 6], 1ull << (r & 63));
    }
}

// ---------------- K5: word-serial greedy resolve (one wave) ----------------
// Greedy NMS with forward-only edges == forward elimination over the 132 rank-words:
// when word w is processed, rem[w] already holds ALL suppressions from kept rows of
// earlier words.  Per word: candidates = ballot(cnt>0) & ~rem[w]; intra-word edges are
// rare (same-word ranks are spatially unrelated), so almost always kept==candidates
// with no serial bit loop; kept lanes then apply their sparse entries IN PARALLEL via
// 64-bit LDS atomicOr.  Serial chain: <=132 word-iterations instead of ~n_nz row-iters.
__global__ __launch_bounds__(64) void nms_kernel(const u64* __restrict__ rowflag_g,
                                                 const u64* __restrict__ validw_g,
                                                 const unsigned int* __restrict__ cnt_g,
                                                 const ulonglong2* __restrict__ ent_g,
                                                 u64* __restrict__ keep_words) {
    __shared__ u64 rem_lds[MASK_WORDS];
    __shared__ unsigned short wlist[MASK_WORDS];
    int lane = threadIdx.x;

    u64 rf[3], vw[3];
    #pragma unroll
    for (int s = 0; s < 3; ++s) {
        int w = s * 64 + lane;
        rf[s] = (w < MASK_WORDS) ? rowflag_g[w] : 0ull;
        vw[s] = (w < MASK_WORDS) ? validw_g[w] : 0ull;
        if (w < MASK_WORDS) rem_lds[w] = 0ull;
    }

    // sorted list of words that contain at least one edge-row
    int base = 0;
    #pragma unroll
    for (int s = 0; s < 3; ++s) {
        bool nz = rf[s] != 0ull;
        u64 bal = __ballot(nz);
        int pos = __popcll(bal & ((1ull << lane) - 1ull));
        if (nz) wlist[base + pos] = (unsigned short)(s * 64 + lane);
        base += (int)__popcll(bal);
    }
    int n_w = base;
    __syncthreads();

    // stage loader: word index, per-lane cnt, first two entries, local (own-word) bits.
    // Per-row entries have distinct target words, so at most one entry is "local";
    // it can sit at ANY index (pairs blocks run in arbitrary order), so scan them all.
    auto LOADW = [&](int t, int &wd, unsigned &c, ulonglong2 &e0, ulonglong2 &e1, u64 &lb) {
        wd = 0; c = 0u; e0.x = 0ull; e0.y = 0ull; e1.x = 0ull; e1.y = 0ull; lb = 0ull;
        if (t < n_w) {
            wd = (int)wlist[t];
            int row = wd * 64 + lane;
            if (row < N_TOT) {
                c = cnt_g[row];
                if (c > 0u) { e0 = ent_g[(size_t)row * CAP];     if ((int)e0.y == wd) lb |= e0.x; }
                if (c > 1u) { e1 = ent_g[(size_t)row * CAP + 1]; if ((int)e1.y == wd) lb |= e1.x; }
                if (c > 2u) {                                   // rare overflow rows
                    unsigned cm = min(c, (unsigned)CAP);
                    for (unsigned e = 2; e < cm; ++e) {
                        ulonglong2 g = ent_g[(size_t)row * CAP + e];
                        if ((int)g.y == wd) lb |= g.x;
                    }
                }
            }
        }
    };

    int wA, wB; unsigned cA, cB; ulonglong2 eA0, eA1, eB0, eB1; u64 lbA, lbB;
    LOADW(0, wA, cA, eA0, eA1, lbA);
    LOADW(1, wB, cB, eB0, eB1, lbB);

    for (int t = 0; t < n_w; ++t) {
        int wC; unsigned cC; ulonglong2 eC0, eC1; u64 lbC;
        LOADW(t + 2, wC, cC, eC0, eC1, lbC);          // prefetch 2 ahead

        __syncthreads();                               // all prior ds_or complete
        u64 remw = rem_lds[wA];                        // broadcast read, now final
        u64 cand = __ballot(cA > 0u) & ~remw;          // edge-rows not yet suppressed
        if (cand) {
            u64 kept;
            u64 localmask = __ballot(lbA != 0ull) & cand;
            if (localmask == 0ull) {
                kept = cand;                           // common case: no intra-word edges
            } else {
                // exact greedy within the word (rare)
                kept = 0ull;
                u64 remw_new = remw;
                u64 pend = cand;
                while (pend) {
                    int b = __builtin_ctzll(pend);
                    pend &= pend - 1ull;
                    if (!((remw_new >> b) & 1ull)) {
                        kept |= 1ull << b;
                        unsigned lo = (unsigned)__builtin_amdgcn_readlane((int)(unsigned)lbA, b);
                        unsigned hi = (unsigned)__builtin_amdgcn_readlane((int)(unsigned)(lbA >> 32), b);
                        remw_new |= ((u64)hi << 32) | (u64)lo;
                        pend &= ~remw_new;
                    }
                }
                if (lane == 0) rem_lds[wA] = remw_new; // own word is final after this
            }
            // parallel far-edge application (all kept lanes at once)
            if ((kept >> lane) & 1ull) {
                if (cA > 0u) { int yw = (int)eA0.y; if (yw != wA) atomicOr(&rem_lds[yw], eA0.x); }
                if (cA > 1u) { int yw = (int)eA1.y; if (yw != wA) atomicOr(&rem_lds[yw], eA1.x); }
                if (cA > 2u) {
                    unsigned cm = min(cA, (unsigned)CAP);
                    int row = wA * 64 + lane;
                    for (unsigned e = 2; e < cm; ++e) {
                        ulonglong2 g = ent_g[(size_t)row * CAP + e];
                        int yw = (int)g.y;
                        if (yw != wA) atomicOr(&rem_lds[yw], g.x);
                    }
                }
            }
        }
        wA = wB; cA = cB; eA0 = eB0; eA1 = eB1; lbA = lbB;
        wB = wC; cB = cC; eB0 = eC0; eB1 = eC1; lbB = lbC;
    }

    __syncthreads();
    #pragma unroll
    for (int s = 0; s < 3; ++s) {
        int w = s * 64 + lane;
        if (w < MASK_WORDS) keep_words[w] = vw[s] & ~rem_lds[w];
    }
}

// ---------------- K6: write outputs ----------------
__global__ void output_kernel(const float* __restrict__ s_sig, const float* __restrict__ s_box,
                              const float* __restrict__ s_kps,
                              const u64* __restrict__ keep_words,
                              float* __restrict__ out) {
    int r = blockIdx.x * blockDim.x + threadIdx.x;
    if (r >= N_TOT) return;
    float m = ((keep_words[r >> 6] >> (r & 63)) & 1ull) ? 1.0f : 0.0f;
    float* ob = out;                   // 8400*4
    float* os = out + 33600;           // 8400
    float* okp = out + 42000;          // 8400*10
    float* om = out + 126000;          // 8400
    #pragma unroll
    for (int c = 0; c < 4; ++c)  ob[r*4+c] = s_box[r*4+c] * m;
    os[r] = s_sig[r] * m;
    #pragma unroll
    for (int c = 0; c < 10; ++c) okp[r*10+c] = s_kps[r*10+c] * m;
    om[r] = m;
}

extern "C" void kernel_launch(void* const* d_in, const int* in_sizes, int n_in,
                              void* d_out, int out_size, void* d_ws, size_t ws_size,
                              hipStream_t stream) {
    const float *score0, *bbox0, *kps0, *score1, *bbox1, *kps1, *score2, *bbox2, *kps2;
    if (in_sizes[1] == 25600) {
        score0 = (const float*)d_in[0]; bbox0 = (const float*)d_in[1]; kps0 = (const float*)d_in[2];
        score1 = (const float*)d_in[3]; bbox1 = (const float*)d_in[4]; kps1 = (const float*)d_in[5];
        score2 = (const float*)d_in[6]; bbox2 = (const float*)d_in[7]; kps2 = (const float*)d_in[8];
    } else {
        score0 = (const float*)d_in[0]; score1 = (const float*)d_in[1]; score2 = (const float*)d_in[2];
        bbox0  = (const float*)d_in[3]; bbox1  = (const float*)d_in[4]; bbox2  = (const float*)d_in[5];
        kps0   = (const float*)d_in[6]; kps1   = (const float*)d_in[7]; kps2   = (const float*)d_in[8];
    }

    char* ws = (char*)d_ws;
    float* logit   = (float*)(ws + 0);
    float* sig     = (float*)(ws + 33600);
    float* box     = (float*)(ws + 67200);
    float* kps     = (float*)(ws + 201600);
    int*   rank    = (int*)  (ws + 537600);
    float* s_logit = (float*)(ws + 571200);
    float* s_sig   = (float*)(ws + 604800);
    float* s_box   = (float*)(ws + 638400);          // 16B-aligned (float4 loads)
    float* s_kps   = (float*)(ws + 772800);          // ends 1108800
    u64*   keep_words = (u64*)(ws + 1108800);        // 1056 B
    u64*   validw     = (u64*)(ws + 1110144);        // 1056 B
    u64*   rowflag    = (u64*)(ws + 1111296);        // 1056 B
    unsigned int* cnt = (unsigned int*)(ws + 1112448);   // 33600 B
    u64*   key        = (u64*)(ws + 1146368);            // 67200 B
    ulonglong2*   ent = (ulonglong2*)(ws + 1213568);     // 8400*32*16 = 4.3 MB

    float* out = (float*)d_out;

    decode_kernel<<<(N_TOT + 255) / 256, 256, 0, stream>>>(
        score0, bbox0, kps0, score1, bbox1, kps1, score2, bbox2, kps2,
        logit, sig, box, kps, key, rank, cnt, validw, rowflag);
    rank_kernel<<<dim3(RT, RT), 256, 0, stream>>>(key, rank);
    scatter_kernel<<<33, 256, 0, stream>>>(rank, logit, sig, box, kps,
                                           s_logit, s_sig, s_box, s_kps, validw);
    pairs_kernel<<<dim3(MASK_WORDS, MASK_WORDS / 2 + 1), 64, 0, stream>>>(s_logit, s_box, cnt, ent, rowflag);
    nms_kernel<<<1, 64, 0, stream>>>(rowflag, validw, cnt, ent, keep_words);
    output_kernel<<<33, 256, 0, stream>>>(s_sig, s_box, s_kps, keep_words, out);
}